// Round 7
// baseline (77.225 us; speedup 1.0000x reference)
//
#include <hip/hip_runtime.h>
#include <hip/hip_bf16.h>

#define NB 256      // batch == queries == classes
#define NL 256      // clips
#define SCALE 100.0f  // 1/TAU

typedef __attribute__((ext_vector_type(4))) unsigned int u32x4;
typedef __attribute__((ext_vector_type(8))) __bf16 bfrag8;
typedef __attribute__((ext_vector_type(4))) float f32x4;

union BU { bfrag8 f; u32x4 u; };

static __device__ __forceinline__ unsigned int pack2bf(float a, float b) {
  union { float f; unsigned int u; } ua, ub;
  ua.f = a; ub.f = b;
  unsigned int ra = (ua.u + 0x7FFFu + ((ua.u >> 16) & 1u)) >> 16;
  unsigned int rb = (ub.u + 0x7FFFu + ((ub.u >> 16) & 1u)) & 0xFFFF0000u;
  return ra | rb;
}

// async 16B global->LDS (gfx950). LDS dest must be wave-uniform.
static __device__ __forceinline__ void gld_lds16(const void* g, void* l) {
  __builtin_amdgcn_global_load_lds(
      (const __attribute__((address_space(1))) unsigned int*)g,
      (__attribute__((address_space(3))) unsigned int*)l, 16, 0, 0);
}

// ---------------------------------------------------------------------------
// Kernel 1: exp-transpose.  WS LAYOUT CHANGE (the round-7 fix): dst[b][i][l]
// — each block writes its OWN contiguous 128KB slab.  Rounds 3-6 used
// [i][b][l]: every store inst hit 8 lines at 128KB stride -> every 128B line
// opened a fresh DRAM row -> write path pinned all variants at ~57us.
// Compute/staging = round-5 structure (proven conflict-free).
// ---------------------------------------------------------------------------
__global__ __launch_bounds__(1024, 2) void exp_t(
    const float* __restrict__ x, const float* __restrict__ tgt,
    unsigned int* __restrict__ xsT, unsigned int* __restrict__ tsT)
{
  const int b = blockIdx.x;
  const bool is_t = (blockIdx.y != 0);
  const int tid = threadIdx.x;
  const int i = tid & 255;
  const int h = tid >> 8;
  const float* src = (is_t ? tgt : x) + (size_t)b * (NL * NB) + i;
  unsigned int* dstb = (is_t ? tsT : xsT);  // u32 units, layout [b][i][l/2]

  __shared__ __align__(16) unsigned char stg[256 * 128];  // [i][64 l] bf16, swizzled

  const int r0 = tid >> 3;  // writer rows r0 and r0+128
  const int c  = tid & 7;   // writer 16B chunk within 128B row-segment

  for (int lc = 0; lc < 4; ++lc) {
    float v[16];
    #pragma unroll
    for (int k = 0; k < 16; ++k)
      v[k] = __expf(src[(size_t)(lc * 64 + h * 16 + k) * NB]);
    u32x4 p0, p1;
    p0.x = pack2bf(v[0], v[1]);   p0.y = pack2bf(v[2], v[3]);
    p0.z = pack2bf(v[4], v[5]);   p0.w = pack2bf(v[6], v[7]);
    p1.x = pack2bf(v[8], v[9]);   p1.y = pack2bf(v[10], v[11]);
    p1.z = pack2bf(v[12], v[13]); p1.w = pack2bf(v[14], v[15]);
    *reinterpret_cast<u32x4*>(&stg[i * 128 + (((h * 2 + 0) ^ (i & 7)) << 4)]) = p0;
    *reinterpret_cast<u32x4*>(&stg[i * 128 + (((h * 2 + 1) ^ (i & 7)) << 4)]) = p1;
    __syncthreads();
    // write out: 256 i-rows x 128B, contiguous within this block's slab
    u32x4 q0 = *reinterpret_cast<const u32x4*>(&stg[r0 * 128 + ((c ^ (r0 & 7)) << 4)]);
    u32x4 q1 = *reinterpret_cast<const u32x4*>(&stg[(r0 + 128) * 128 + ((c ^ ((r0 + 128) & 7)) << 4)]);
    *reinterpret_cast<u32x4*>(dstb + ((size_t)b * 256 + r0) * 128 + lc * 32 + c * 4) = q0;
    *reinterpret_cast<u32x4*>(dstb + ((size_t)b * 256 + r0 + 128) * 128 + lc * 32 + c * 4) = q1;
    __syncthreads();
  }
}

// ---------------------------------------------------------------------------
// Kernel 2: per-i NT GEMM on unnormalized exp values (ws layout [b][i][l]:
// row r of a panel lives at ((r*256+i)*256) elements — 128KB stride, L3-hot).
//   raw[j,c]  = sum_l (ex[j,l] & m[l]) * et[c,l]
//   rowsum[j] = MFMA(af, ones);  colsum[c] = MFMA(ones, bfr)
//   logits    = SCALE * raw * rcp(rowsum) * rcp(colsum)  -> LSE -> diag pick.
// Round-7: async global_load_lds staging, pre-swizzled SOURCE + linear LDS
// dest (dest byte = t*16 exactly; XOR involution applied on read — rule #21).
// B double-buffered; A staged behind an lgkmcnt-only raw barrier so B-stage
// vmcnt stays in flight across it (T3-lite).  LDS 76.5KB -> 2 blocks/CU.
// ---------------------------------------------------------------------------
__global__ __launch_bounds__(256, 2) void gemm_lse(
    const unsigned short* __restrict__ xsT,
    const unsigned short* __restrict__ tsT,
    const int* __restrict__ mask,
    const int* __restrict__ label_mat,
    float* __restrict__ out)
{
  // XCD-aware decode: all 4 jt-blocks of one i share an XCD residue.
  const int n  = blockIdx.x;
  const int g  = n & 7;
  const int q  = n >> 3;
  const int i  = ((q >> 2) << 3) + g;
  const int jt = q & 3;
  const int t  = threadIdx.x;
  const int w  = t >> 6;
  const int lane = t & 63;

  __shared__ __align__(16) unsigned char As[64 * 128];        // [64 j][64 l] swizzled
  __shared__ __align__(16) unsigned char Bs[2][256 * 128];    // [256 c][64 l] swizzled, dbuf
  __shared__ __align__(16) unsigned short s_mask[NL];
  __shared__ float s_rmax[4][64];
  __shared__ float s_rsum[4][64];
  __shared__ float s_diag[64];

  const int srow = t >> 3;       // staging row base
  const int sch  = t & 7;        // staging 16B-chunk within row

  s_mask[t] = (mask[i * NL + t] > 0) ? (unsigned short)0xFFFFu : (unsigned short)0u;

  BU onesbu;
  onesbu.u = u32x4{0x3F803F80u, 0x3F803F80u, 0x3F803F80u, 0x3F803F80u};
  const bfrag8 ones = onesbu.f;

  f32x4 acc[4][4], acc_as[4], acc_bs[4];
  #pragma unroll
  for (int a = 0; a < 4; ++a) {
    acc_as[a] = f32x4{0.f, 0.f, 0.f, 0.f};
    acc_bs[a] = f32x4{0.f, 0.f, 0.f, 0.f};
    #pragma unroll
    for (int cc = 0; cc < 4; ++cc) acc[a][cc] = f32x4{0.f, 0.f, 0.f, 0.f};
  }

  // stage chunk kc2 of B into Bs[buf]: 8 async 16B loads/thread, source
  // pre-swizzled so linear LDS dest yields the XOR-swizzled layout.
  auto stage_B = [&](int buf, int kc2) {
    const int kofs = kc2 * 64;
    #pragma unroll
    for (int r = 0; r < 8; ++r) {
      int row = srow + r * 32;
      int schp = sch ^ (row & 7);
      gld_lds16(tsT + ((size_t)row * 256 + i) * 256 + kofs + schp * 8,
                &Bs[buf][w * 1024 + r * 4096]);
    }
  };
  auto stage_A = [&](int kc2) {
    const int kofs = kc2 * 64;
    #pragma unroll
    for (int r = 0; r < 2; ++r) {
      int arow = srow + r * 32;
      int schp = sch ^ (arow & 7);
      gld_lds16(xsT + ((size_t)(jt * 64 + arow) * 256 + i) * 256 + kofs + schp * 8,
                &As[w * 1024 + r * 4096]);
    }
  };

  // prologue: stage A+B chunk 0, full drain
  stage_B(0, 0);
  stage_A(0);
  __syncthreads();   // vmcnt(0)+lgkmcnt(0)+barrier: chunk 0 + s_mask ready

  #pragma unroll
  for (int kc = 0; kc < 4; ++kc) {
    const int cur = kc & 1;
    // 1. async-stage next B chunk into the other buffer
    if (kc < 3) stage_B(cur ^ 1, kc + 1);
    // 2. read this chunk's A fragments (both kk) into registers
    bfrag8 af0[4], af1[4];
    #pragma unroll
    for (int jf = 0; jf < 4; ++jf) {
      int row = jf * 16 + (lane & 15);
      int co0 = 0 * 4 + (lane >> 4), co1 = 1 * 4 + (lane >> 4);
      af0[jf] = *reinterpret_cast<const bfrag8*>(&As[row * 128 + ((co0 ^ (row & 7)) << 4)]);
      af1[jf] = *reinterpret_cast<const bfrag8*>(&As[row * 128 + ((co1 ^ (row & 7)) << 4)]);
    }
    // 3. mid fence: A reads retired wave-wide; B-stage vmcnt stays in flight
    asm volatile("s_waitcnt lgkmcnt(0)" ::: "memory");
    __builtin_amdgcn_sched_barrier(0);
    __builtin_amdgcn_s_barrier();
    // 4. async-stage next A chunk (As memory now free)
    if (kc < 3) stage_A(kc + 1);
    // 5. B fragment reads + MFMAs for kk = 0, 1
    #pragma unroll
    for (int kk = 0; kk < 2; ++kk) {
      const int co = kk * 4 + (lane >> 4);
      bfrag8 bfr[4];
      #pragma unroll
      for (int cf = 0; cf < 4; ++cf) {
        int row = w * 64 + cf * 16 + (lane & 15);
        bfr[cf] = *reinterpret_cast<const bfrag8*>(
            &Bs[cur][row * 128 + ((co ^ (row & 7)) << 4)]);
      }
      u32x4 mk = *reinterpret_cast<const u32x4*>(
          &s_mask[kc * 64 + kk * 32 + ((lane >> 4) << 3)]);
      #pragma unroll
      for (int jf = 0; jf < 4; ++jf) {
        BU am; am.f = (kk == 0) ? af0[jf] : af1[jf]; am.u &= mk;
        #pragma unroll
        for (int cf = 0; cf < 4; ++cf)
          acc[jf][cf] = __builtin_amdgcn_mfma_f32_16x16x32_bf16(
              am.f, bfr[cf], acc[jf][cf], 0, 0, 0);
        acc_as[jf] = __builtin_amdgcn_mfma_f32_16x16x32_bf16(
            (kk == 0) ? af0[jf] : af1[jf], ones, acc_as[jf], 0, 0, 0);
      }
      #pragma unroll
      for (int cf = 0; cf < 4; ++cf)
        acc_bs[cf] = __builtin_amdgcn_mfma_f32_16x16x32_bf16(
            ones, bfr[cf], acc_bs[cf], 0, 0, 0);
    }
    // 6. end fence: all staging (A+B) landed in LDS
    asm volatile("s_waitcnt vmcnt(0)" ::: "memory");
    __builtin_amdgcn_sched_barrier(0);
    __builtin_amdgcn_s_barrier();
  }

  // ---- epilogue: logits = SCALE * raw * invx[row] * invt[col] ----
  float ixv[4][4];
  #pragma unroll
  for (int jf = 0; jf < 4; ++jf)
    #pragma unroll
    for (int reg = 0; reg < 4; ++reg)
      ixv[jf][reg] = __builtin_amdgcn_rcpf(acc_as[jf][reg]) * SCALE;
  float itv[4];
  #pragma unroll
  for (int cf = 0; cf < 4; ++cf)
    itv[cf] = __builtin_amdgcn_rcpf(acc_bs[cf][0]);
  #pragma unroll
  for (int jf = 0; jf < 4; ++jf)
    #pragma unroll
    for (int cf = 0; cf < 4; ++cf)
      #pragma unroll
      for (int reg = 0; reg < 4; ++reg)
        acc[jf][cf][reg] *= ixv[jf][reg] * itv[cf];

  const int rg = (lane >> 4) << 2;  // this lane holds rows jf*16 + rg + reg

  #pragma unroll
  for (int jf = 0; jf < 4; ++jf) {
    #pragma unroll
    for (int reg = 0; reg < 4; ++reg) {
      float m = fmaxf(fmaxf(acc[jf][0][reg], acc[jf][1][reg]),
                      fmaxf(acc[jf][2][reg], acc[jf][3][reg]));
      #pragma unroll
      for (int off = 1; off < 16; off <<= 1) m = fmaxf(m, __shfl_xor(m, off, 64));
      if ((lane & 15) == 0) s_rmax[w][jf * 16 + rg + reg] = m;
    }
  }
  // diag c == i: wave i>>6, frag (i>>4)&3, lanes lane&15 == i&15 (rule #20:
  // predicated select, compile-time indices only).
  if (w == (i >> 6) && (lane & 15) == (i & 15)) {
    const int cfd = (i >> 4) & 3;
    #pragma unroll
    for (int jf = 0; jf < 4; ++jf) {
      #pragma unroll
      for (int reg = 0; reg < 4; ++reg) {
        float v = acc[jf][0][reg];
        #pragma unroll
        for (int cf = 1; cf < 4; ++cf)
          v = (cfd == cf) ? acc[jf][cf][reg] : v;
        s_diag[jf * 16 + rg + reg] = v;
      }
    }
  }
  __syncthreads();

  #pragma unroll
  for (int jf = 0; jf < 4; ++jf) {
    #pragma unroll
    for (int reg = 0; reg < 4; ++reg) {
      int row = jf * 16 + rg + reg;
      float gm = fmaxf(fmaxf(s_rmax[0][row], s_rmax[1][row]),
                       fmaxf(s_rmax[2][row], s_rmax[3][row]));
      float sE = 0.f;
      #pragma unroll
      for (int cf = 0; cf < 4; ++cf) sE += __expf(acc[jf][cf][reg] - gm);
      #pragma unroll
      for (int off = 1; off < 16; off <<= 1) sE += __shfl_xor(sE, off, 64);
      if ((lane & 15) == 0) s_rsum[w][row] = sE;
    }
  }
  __syncthreads();

  float contrib = 0.f;
  if (t < 64) {
    const int row = t;
    float gm = fmaxf(fmaxf(s_rmax[0][row], s_rmax[1][row]),
                     fmaxf(s_rmax[2][row], s_rmax[3][row]));
    float tot = s_rsum[0][row] + s_rsum[1][row] + s_rsum[2][row] + s_rsum[3][row];
    float lse = __logf(tot) + gm;
    float lbl = (float)label_mat[i * NB + jt * 64 + row];
    contrib = lbl * (s_diag[row] - lse);
  }
  #pragma unroll
  for (int off = 32; off >= 1; off >>= 1) contrib += __shfl_down(contrib, off, 64);
  if (t == 0) atomicAdd(out, contrib * (-1.0f / 256.0f));
}

extern "C" void kernel_launch(void* const* d_in, const int* in_sizes, int n_in,
                              void* d_out, int out_size, void* d_ws, size_t ws_size,
                              hipStream_t stream) {
  const float* x   = (const float*)d_in[0];
  const float* tgt = (const float*)d_in[1];
  const int* mask  = (const int*)d_in[2];
  // d_in[3] = query_labels (unused by the reference computation)
  const int* label_mat = (const int*)d_in[4];
  float* out = (float*)d_out;

  unsigned int* xsT = (unsigned int*)d_ws;                       // 32 MiB bf16 [b][i][l]
  unsigned int* tsT = xsT + (size_t)NB * NB * NL / 2;            // 32 MiB bf16 [b][i][l]

  hipMemsetAsync(out, 0, sizeof(float), stream);
  exp_t<<<dim3(NB, 2), 1024, 0, stream>>>(x, tgt, xsT, tsT);
  gemm_lse<<<dim3(1024), 256, 0, stream>>>((const unsigned short*)xsT,
                                           (const unsigned short*)tsT,
                                           mask, label_mat, out);
}

// Round 8
// 76.862 us; speedup vs baseline: 1.0047x; 1.0047x over previous
//
#include <hip/hip_runtime.h>
#include <hip/hip_bf16.h>

#define NB 256      // batch == queries == classes
#define NL 256      // clips
#define SCALE 100.0f  // 1/TAU

typedef __attribute__((ext_vector_type(4))) unsigned int u32x4;
typedef __attribute__((ext_vector_type(8))) __bf16 bfrag8;
typedef __attribute__((ext_vector_type(4))) float f32x4;

union BU { bfrag8 f; u32x4 u; };

static __device__ __forceinline__ unsigned int pack2bf(float a, float b) {
  union { float f; unsigned int u; } ua, ub;
  ua.f = a; ub.f = b;
  unsigned int ra = (ua.u + 0x7FFFu + ((ua.u >> 16) & 1u)) >> 16;
  unsigned int rb = (ub.u + 0x7FFFu + ((ub.u >> 16) & 1u)) & 0xFFFF0000u;
  return ra | rb;
}

// ---------------------------------------------------------------------------
// Kernel 1: exp-transpose (unchanged from round 7 — improved there).
// dst[b][i][l] = bf16(exp(src[b,l,i])): each block writes its own contiguous
// 128KB slab (full-line, row-local stores).
// ---------------------------------------------------------------------------
__global__ __launch_bounds__(1024, 2) void exp_t(
    const float* __restrict__ x, const float* __restrict__ tgt,
    unsigned int* __restrict__ xsT, unsigned int* __restrict__ tsT)
{
  const int b = blockIdx.x;
  const bool is_t = (blockIdx.y != 0);
  const int tid = threadIdx.x;
  const int i = tid & 255;
  const int h = tid >> 8;
  const float* src = (is_t ? tgt : x) + (size_t)b * (NL * NB) + i;
  unsigned int* dstb = (is_t ? tsT : xsT);  // u32 units, layout [b][i][l/2]

  __shared__ __align__(16) unsigned char stg[256 * 128];  // [i][64 l] bf16, swizzled

  const int r0 = tid >> 3;  // writer rows r0 and r0+128
  const int c  = tid & 7;   // writer 16B chunk within 128B row-segment

  for (int lc = 0; lc < 4; ++lc) {
    float v[16];
    #pragma unroll
    for (int k = 0; k < 16; ++k)
      v[k] = __expf(src[(size_t)(lc * 64 + h * 16 + k) * NB]);
    u32x4 p0, p1;
    p0.x = pack2bf(v[0], v[1]);   p0.y = pack2bf(v[2], v[3]);
    p0.z = pack2bf(v[4], v[5]);   p0.w = pack2bf(v[6], v[7]);
    p1.x = pack2bf(v[8], v[9]);   p1.y = pack2bf(v[10], v[11]);
    p1.z = pack2bf(v[12], v[13]); p1.w = pack2bf(v[14], v[15]);
    *reinterpret_cast<u32x4*>(&stg[i * 128 + (((h * 2 + 0) ^ (i & 7)) << 4)]) = p0;
    *reinterpret_cast<u32x4*>(&stg[i * 128 + (((h * 2 + 1) ^ (i & 7)) << 4)]) = p1;
    __syncthreads();
    u32x4 q0 = *reinterpret_cast<const u32x4*>(&stg[r0 * 128 + ((c ^ (r0 & 7)) << 4)]);
    u32x4 q1 = *reinterpret_cast<const u32x4*>(&stg[(r0 + 128) * 128 + ((c ^ ((r0 + 128) & 7)) << 4)]);
    *reinterpret_cast<u32x4*>(dstb + ((size_t)b * 256 + r0) * 128 + lc * 32 + c * 4) = q0;
    *reinterpret_cast<u32x4*>(dstb + ((size_t)b * 256 + r0 + 128) * 128 + lc * 32 + c * 4) = q1;
    __syncthreads();
  }
}

// ---------------------------------------------------------------------------
// Kernel 2 (round-8 restructure: OCCUPANCY).  Rounds 5-7 all pinned at ~57us
// with MfmaUtil 8% / VALU 13% / Occ 18% (2 waves/SIMD) across three staging
// schemes -> latency-bound, not staging-bound.  Now: 512 blocks x 512 threads
// (8 waves), block tile 128j x 256c (jt in {0,1}), wave tile 64j x 64c,
// single-buffered LDS (~54KB -> 2 blocks/CU) = 16 waves/CU, 4/SIMD (2x).
//   raw[j,c]  = sum_l (ex[j,l] & m[l]) * et[c,l]
//   rowsum[j] = MFMA(af, ones);  colsum[c] = MFMA(ones, bfr)
//   logits    = SCALE * raw * rcp(rowsum) * rcp(colsum) -> LSE -> diag pick.
// rule #20: all acc indexing compile-time (diag = predicated select).
// ---------------------------------------------------------------------------
__global__ __launch_bounds__(512, 2) void gemm_lse(
    const unsigned short* __restrict__ xsT,
    const unsigned short* __restrict__ tsT,
    const int* __restrict__ mask,
    const int* __restrict__ label_mat,
    float* __restrict__ out)
{
  // XCD-aware decode: both jt-halves of one i share an XCD residue.
  const int n  = blockIdx.x;
  const int g  = n & 7;
  const int q  = n >> 3;
  const int i  = ((q >> 1) << 3) + g;
  const int jt = q & 1;
  const int t  = threadIdx.x;
  const int w  = t >> 6;
  const int lane = t & 63;
  const int wr = w >> 2;   // j-group (0..1)
  const int wc = w & 3;    // c-group (0..3)

  __shared__ __align__(16) unsigned char As[128 * 128];   // [128 j][64 l] bf16, swizzled
  __shared__ __align__(16) unsigned char Bs[256 * 128];   // [256 c][64 l] bf16, swizzled
  __shared__ __align__(16) unsigned short s_mask[NL];
  __shared__ float s_rmax[4][128];
  __shared__ float s_rsum[4][128];
  __shared__ float s_diag[128];

  if (t < 256)
    s_mask[t] = (mask[i * NL + t] > 0) ? (unsigned short)0xFFFFu : (unsigned short)0u;

  BU onesbu;
  onesbu.u = u32x4{0x3F803F80u, 0x3F803F80u, 0x3F803F80u, 0x3F803F80u};
  const bfrag8 ones = onesbu.f;

  f32x4 acc[4][4], acc_as[4], acc_bs[4];
  #pragma unroll
  for (int a = 0; a < 4; ++a) {
    acc_as[a] = f32x4{0.f, 0.f, 0.f, 0.f};
    acc_bs[a] = f32x4{0.f, 0.f, 0.f, 0.f};
    #pragma unroll
    for (int cc = 0; cc < 4; ++cc) acc[a][cc] = f32x4{0.f, 0.f, 0.f, 0.f};
  }

  u32x4 areg[2], breg[4];

  auto load_chunk = [&](int kc) {
    const int kofs = kc * 64;
    #pragma unroll
    for (int r = 0; r < 2; ++r) {
      int u = t + r * 512;                 // A: 128 rows x 8 chunks
      int row = u >> 3, ch = u & 7;
      areg[r] = *reinterpret_cast<const u32x4*>(
          xsT + ((size_t)(jt * 128 + row) * 256 + i) * 256 + kofs + ch * 8);
    }
    #pragma unroll
    for (int r = 0; r < 4; ++r) {
      int u = t + r * 512;                 // B: 256 rows x 8 chunks
      int row = u >> 3, ch = u & 7;
      breg[r] = *reinterpret_cast<const u32x4*>(
          tsT + ((size_t)row * 256 + i) * 256 + kofs + ch * 8);
    }
  };
  auto store_chunk = [&]() {
    #pragma unroll
    for (int r = 0; r < 2; ++r) {
      int u = t + r * 512;
      int row = u >> 3, ch = u & 7;
      *reinterpret_cast<u32x4*>(&As[row * 128 + ((ch ^ (row & 7)) << 4)]) = areg[r];
    }
    #pragma unroll
    for (int r = 0; r < 4; ++r) {
      int u = t + r * 512;
      int row = u >> 3, ch = u & 7;
      *reinterpret_cast<u32x4*>(&Bs[row * 128 + ((ch ^ (row & 7)) << 4)]) = breg[r];
    }
  };

  load_chunk(0);
  #pragma unroll
  for (int kc = 0; kc < 4; ++kc) {
    store_chunk();
    __syncthreads();                       // LDS chunk + s_mask visible
    if (kc < 3) load_chunk(kc + 1);        // next loads fly under the MFMAs
    #pragma unroll
    for (int kk = 0; kk < 2; ++kk) {
      const int co = kk * 4 + (lane >> 4);
      bfrag8 af[4], bfr[4];
      #pragma unroll
      for (int jf = 0; jf < 4; ++jf) {
        int row = wr * 64 + jf * 16 + (lane & 15);
        af[jf] = *reinterpret_cast<const bfrag8*>(
            &As[row * 128 + ((co ^ (row & 7)) << 4)]);
      }
      #pragma unroll
      for (int cf = 0; cf < 4; ++cf) {
        int row = wc * 64 + cf * 16 + (lane & 15);
        bfr[cf] = *reinterpret_cast<const bfrag8*>(
            &Bs[row * 128 + ((co ^ (row & 7)) << 4)]);
      }
      u32x4 mk = *reinterpret_cast<const u32x4*>(
          &s_mask[kc * 64 + kk * 32 + ((lane >> 4) << 3)]);
      #pragma unroll
      for (int jf = 0; jf < 4; ++jf) {
        BU am; am.f = af[jf]; am.u &= mk;
        #pragma unroll
        for (int cf = 0; cf < 4; ++cf)
          acc[jf][cf] = __builtin_amdgcn_mfma_f32_16x16x32_bf16(
              am.f, bfr[cf], acc[jf][cf], 0, 0, 0);
        acc_as[jf] = __builtin_amdgcn_mfma_f32_16x16x32_bf16(
            af[jf], ones, acc_as[jf], 0, 0, 0);   // unmasked row sums
      }
      #pragma unroll
      for (int cf = 0; cf < 4; ++cf)
        acc_bs[cf] = __builtin_amdgcn_mfma_f32_16x16x32_bf16(
            ones, bfr[cf], acc_bs[cf], 0, 0, 0);  // unmasked col sums
    }
    if (kc < 3) __syncthreads();           // MFMA reads done before next store
  }

  // ---- epilogue: logits = SCALE * raw * invx[row] * invt[col] ----
  float ixv[4][4];
  #pragma unroll
  for (int jf = 0; jf < 4; ++jf)
    #pragma unroll
    for (int reg = 0; reg < 4; ++reg)
      ixv[jf][reg] = __builtin_amdgcn_rcpf(acc_as[jf][reg]) * SCALE;
  float itv[4];
  #pragma unroll
  for (int cf = 0; cf < 4; ++cf)
    itv[cf] = __builtin_amdgcn_rcpf(acc_bs[cf][0]);
  #pragma unroll
  for (int jf = 0; jf < 4; ++jf)
    #pragma unroll
    for (int cf = 0; cf < 4; ++cf)
      #pragma unroll
      for (int reg = 0; reg < 4; ++reg)
        acc[jf][cf][reg] *= ixv[jf][reg] * itv[cf];

  const int rg = (lane >> 4) << 2;  // lane holds rows wr*64 + jf*16 + rg + reg

  #pragma unroll
  for (int jf = 0; jf < 4; ++jf) {
    #pragma unroll
    for (int reg = 0; reg < 4; ++reg) {
      float m = fmaxf(fmaxf(acc[jf][0][reg], acc[jf][1][reg]),
                      fmaxf(acc[jf][2][reg], acc[jf][3][reg]));
      #pragma unroll
      for (int off = 1; off < 16; off <<= 1) m = fmaxf(m, __shfl_xor(m, off, 64));
      if ((lane & 15) == 0) s_rmax[wc][wr * 64 + jf * 16 + rg + reg] = m;
    }
  }
  // diag col c == i lives in waves with wc == i>>6, frag (i>>4)&3, lanes
  // (lane&15) == i&15 (rule #20: predicated select, compile-time indices).
  if (wc == (i >> 6) && (lane & 15) == (i & 15)) {
    const int cfd = (i >> 4) & 3;
    #pragma unroll
    for (int jf = 0; jf < 4; ++jf) {
      #pragma unroll
      for (int reg = 0; reg < 4; ++reg) {
        float v = acc[jf][0][reg];
        #pragma unroll
        for (int cf = 1; cf < 4; ++cf)
          v = (cfd == cf) ? acc[jf][cf][reg] : v;
        s_diag[wr * 64 + jf * 16 + rg + reg] = v;
      }
    }
  }
  __syncthreads();

  #pragma unroll
  for (int jf = 0; jf < 4; ++jf) {
    #pragma unroll
    for (int reg = 0; reg < 4; ++reg) {
      int row = wr * 64 + jf * 16 + rg + reg;
      float gm = fmaxf(fmaxf(s_rmax[0][row], s_rmax[1][row]),
                       fmaxf(s_rmax[2][row], s_rmax[3][row]));
      float sE = 0.f;
      #pragma unroll
      for (int cf = 0; cf < 4; ++cf) sE += __expf(acc[jf][cf][reg] - gm);
      #pragma unroll
      for (int off = 1; off < 16; off <<= 1) sE += __shfl_xor(sE, off, 64);
      if ((lane & 15) == 0) s_rsum[wc][row] = sE;
    }
  }
  __syncthreads();

  float contrib = 0.f;
  if (t < 128) {
    const int row = t;
    float gm = fmaxf(fmaxf(s_rmax[0][row], s_rmax[1][row]),
                     fmaxf(s_rmax[2][row], s_rmax[3][row]));
    float tot = s_rsum[0][row] + s_rsum[1][row] + s_rsum[2][row] + s_rsum[3][row];
    float lse = __logf(tot) + gm;
    float lbl = (float)label_mat[i * NB + jt * 128 + row];
    contrib = lbl * (s_diag[row] - lse);
  }
  #pragma unroll
  for (int off = 32; off >= 1; off >>= 1) contrib += __shfl_down(contrib, off, 64);
  if (lane == 0 && w < 2) atomicAdd(out, contrib * (-1.0f / 256.0f));
}

extern "C" void kernel_launch(void* const* d_in, const int* in_sizes, int n_in,
                              void* d_out, int out_size, void* d_ws, size_t ws_size,
                              hipStream_t stream) {
  const float* x   = (const float*)d_in[0];
  const float* tgt = (const float*)d_in[1];
  const int* mask  = (const int*)d_in[2];
  // d_in[3] = query_labels (unused by the reference computation)
  const int* label_mat = (const int*)d_in[4];
  float* out = (float*)d_out;

  unsigned int* xsT = (unsigned int*)d_ws;                       // 32 MiB bf16 [b][i][l]
  unsigned int* tsT = xsT + (size_t)NB * NB * NL / 2;            // 32 MiB bf16 [b][i][l]

  hipMemsetAsync(out, 0, sizeof(float), stream);
  exp_t<<<dim3(NB, 2), 1024, 0, stream>>>(x, tgt, xsT, tsT);
  gemm_lse<<<dim3(512), 512, 0, stream>>>((const unsigned short*)xsT,
                                          (const unsigned short*)tsT,
                                          mask, label_mat, out);
}